// Round 8
// baseline (20658.401 us; speedup 1.0000x reference)
//
#include <hip/hip_runtime.h>
#include <math.h>

#define H 2048
#define S 8192
#define RPB 32             // hidden rows per block
#define NBLK (H / RPB)     // 64 blocks
#define TPB 512            // 8 waves/block; thread polls ONE 16B chunk
#define PARBYTES (H * 4)   // 8 KB per parity buffer (2048 packed fp32)
#define NREP 2             // hvt replicas
// ws layout (bytes): [rep][parity][PARBYTES] = 2*2*8KB = 32 KB

typedef unsigned int u32x4 __attribute__((ext_vector_type(4)));

// ---------------------------------------------------------------------------
// GEMM: U[t][j] = sum_k X[t][k] * Wxh[j][k]  (unchanged; ~1 ms, not the bottleneck)
// ---------------------------------------------------------------------------
__global__ __launch_bounds__(256) void gemm_xw(const float* __restrict__ X,
                                               const float* __restrict__ W,
                                               float* __restrict__ U) {
    __shared__ float As[16][64];
    __shared__ float Bs[16][64];
    const int tid = threadIdx.x;
    const int t0 = blockIdx.x * 64;
    const int j0 = blockIdx.y * 64;
    const int tx = tid & 15, ty = tid >> 4;

    float acc[4][4] = {};
    const int lr = tid >> 2;
    const int lk = (tid & 3) * 4;

    for (int k0 = 0; k0 < H; k0 += 16) {
        float4 a = *(const float4*)&X[(size_t)(t0 + lr) * H + k0 + lk];
        float4 b = *(const float4*)&W[(size_t)(j0 + lr) * H + k0 + lk];
        As[lk + 0][lr] = a.x; As[lk + 1][lr] = a.y; As[lk + 2][lr] = a.z; As[lk + 3][lr] = a.w;
        Bs[lk + 0][lr] = b.x; Bs[lk + 1][lr] = b.y; Bs[lk + 2][lr] = b.z; Bs[lk + 3][lr] = b.w;
        __syncthreads();
#pragma unroll
        for (int kk = 0; kk < 16; ++kk) {
            float4 av = *(const float4*)&As[kk][ty * 4];
            float4 bv = *(const float4*)&Bs[kk][tx * 4];
            float aa[4] = {av.x, av.y, av.z, av.w};
            float bb[4] = {bv.x, bv.y, bv.z, bv.w};
#pragma unroll
            for (int i = 0; i < 4; ++i)
#pragma unroll
                for (int j = 0; j < 4; ++j)
                    acc[i][j] += aa[i] * bb[j];
        }
        __syncthreads();
    }
#pragma unroll
    for (int i = 0; i < 4; ++i) {
        float4 v = {acc[i][0], acc[i][1], acc[i][2], acc[i][3]};
        *(float4*)&U[(size_t)(t0 + ty * 4 + i) * H + j0 + tx * 4] = v;
    }
}

// ---------------------------------------------------------------------------
// Init. 2-bit epoch e=(t>>1)&3 spread over a 16B chunk's four LSBs as
// [e&1, e>>1, e&1, e>>1]. Parity-0 init = all-zero (h0=0, pattern e=0,
// matches t=0). Parity-1 init = LSB 1 per 4B (pattern e=3, mismatches t=1).
// ---------------------------------------------------------------------------
__global__ void init_ws(unsigned long long* __restrict__ w) {
    int i = blockIdx.x * blockDim.x + threadIdx.x;
    if (i < NREP * 2 * (PARBYTES / 8))
        w[i] = ((i >> 10) & 1) ? 0x0000000100000001ull : 0ull;
}

// ---------------------------------------------------------------------------
// sc1 (LLC-coherent) helpers. Single-chunk poll: minimal round body ->
// detection quantum ~= 1 LLC RTT.
// ---------------------------------------------------------------------------
__device__ inline u32x4 ld16_sc1(const void* p) {
    u32x4 r;
    asm volatile("global_load_dwordx4 %0, %1, off sc1\n\t"
                 "s_waitcnt vmcnt(0)"
                 : "=&v"(r) : "v"(p) : "memory");
    return r;
}
__device__ inline void st16_sc1(void* p, u32x4 v) {
    asm volatile("global_store_dwordx4 %0, %1, off sc1" :: "v"(p), "v"(v) : "memory");
}

// ---------------------------------------------------------------------------
// Persistent recurrence: 64 blocks x 512 threads x 32 rows.
// Re-test of the (confirmed at R6) contention lever at 64 participants, in
// a VGPR-safe geometry: thread polls ONE 16B chunk (512*16B = 8KB) and
// holds wv[32] (128 VGPRs) — ~180 total, one-wave budget, no AGPR pressure
// (R7's 320-VGPR config is the prime suspect for its failure).
// Correctness layers from R6 verbatim:
//   - publisher store-store fence (s_waitcnt vmcnt(0)) before each publish
//   - 2-bit epoch spread -> 8-step alias distance (skew<=1 proof is
//     NBLK-independent: t+2 publishes require ALL threads consumed h_t)
//   - per-4B atomicity + chunk-unit validation (tear-safe)
//   - part[] parity double-buffer; reuse at t+2 gated by global dataflow.
// ---------------------------------------------------------------------------
__global__ __launch_bounds__(TPB, 2) void rnn_recur(float* __restrict__ out,
                                                    const float* __restrict__ Whh,
                                                    const float* __restrict__ bias,
                                                    unsigned long long* __restrict__ hvt) {
    __shared__ float part[2][8][RPB];   // [parity][wave][row]
    const int tid  = threadIdx.x;
    const int lane = tid & 63;
    const int wid  = tid >> 6;
    const int r0   = blockIdx.x * RPB;

    // W fragment: wv[j] = Whh[r0+j][4*tid .. +3]  (128 VGPRs)
    float4 wv[RPB];
#pragma unroll
    for (int j = 0; j < RPB; ++j)
        wv[j] = *(const float4*)&Whh[(size_t)(r0 + j) * H + 4 * tid];

    const float bb = bias[r0 + (tid & 31)];
    char* const hrep = (char*)hvt + (size_t)(blockIdx.x & 1) * (2 * PARBYTES);

    for (int t = 0; t < S; ++t) {
        // Prefetch this step's U value (rows r0..r0+31; hides under poll).
        float u_val = out[(size_t)t * H + r0 + (tid & 31)];

        const unsigned int e  = ((unsigned int)t >> 1) & 3u;
        const unsigned int e0 = e & 1u, e1 = (e >> 1) & 1u;
        const char* pc = hrep + (size_t)(t & 1) * PARBYTES + tid * 16;

        float acc[RPB];
#pragma unroll
        for (int j = 0; j < RPB; ++j) acc[j] = 0.f;

        unsigned int pend = 1u;
        while (pend) {
            const u32x4 v = ld16_sc1(pc);
            if ((((v.x ^ e0) | (v.z ^ e0) | (v.y ^ e1) | (v.w ^ e1)) & 1u) == 0u) {
                const float h0 = __uint_as_float(v.x), h1 = __uint_as_float(v.y);
                const float h2 = __uint_as_float(v.z), h3 = __uint_as_float(v.w);
#pragma unroll
                for (int j = 0; j < RPB; ++j)
                    acc[j] += wv[j].x * h0 + wv[j].y * h1 +
                              wv[j].z * h2 + wv[j].w * h3;
                pend = 0u;
            }
        }

        // Folding butterfly: 32 rows x 64 lanes -> 1 row/lane (depth 6).
#pragma unroll
        for (int j = 0; j < 16; ++j) {
            float s = (lane & 1) ? acc[j] : acc[j + 16];
            float r = __shfl_xor(s, 1, 64);
            acc[j] = ((lane & 1) ? acc[j + 16] : acc[j]) + r;
        }
#pragma unroll
        for (int j = 0; j < 8; ++j) {
            float s = (lane & 2) ? acc[j] : acc[j + 8];
            float r = __shfl_xor(s, 2, 64);
            acc[j] = ((lane & 2) ? acc[j + 8] : acc[j]) + r;
        }
#pragma unroll
        for (int j = 0; j < 4; ++j) {
            float s = (lane & 4) ? acc[j] : acc[j + 4];
            float r = __shfl_xor(s, 4, 64);
            acc[j] = ((lane & 4) ? acc[j + 4] : acc[j]) + r;
        }
#pragma unroll
        for (int j = 0; j < 2; ++j) {
            float s = (lane & 8) ? acc[j] : acc[j + 2];
            float r = __shfl_xor(s, 8, 64);
            acc[j] = ((lane & 8) ? acc[j + 2] : acc[j]) + r;
        }
        {
            float s = (lane & 16) ? acc[0] : acc[1];
            float r = __shfl_xor(s, 16, 64);
            acc[0] = ((lane & 16) ? acc[1] : acc[0]) + r;
        }
        acc[0] += __shfl_xor(acc[0], 32, 64);

        // lane<32 holds row bitrev5(lane&31): lane bit k -> row bit (4-k).
        if (lane < 32) {
            const int row = ((lane & 1) << 4) | ((lane & 2) << 2) | (lane & 4) |
                            ((lane & 8) >> 2) | ((lane & 16) >> 4);
            part[t & 1][wid][row] = acc[0];
        }
        __syncthreads();

        if (tid < RPB) {
            float sum = 0.f;
#pragma unroll
            for (int w = 0; w < 8; ++w) sum += part[t & 1][w][tid];
            const float val = tanhf(sum + u_val + bb);
            // Gather 4 adjacent rows into one 16B word; every 4th thread stores.
            const float s0 = __shfl(val, (tid & 28) | 0, 64);
            const float s1 = __shfl(val, (tid & 28) | 1, 64);
            const float s2 = __shfl(val, (tid & 28) | 2, 64);
            const float s3 = __shfl(val, (tid & 28) | 3, 64);
            if ((tid & 3) == 0) {
                const unsigned int ee  = (((unsigned int)(t + 1)) >> 1) & 3u;
                const unsigned int ee0 = ee & 1u, ee1 = (ee >> 1) & 1u;
                u32x4 pk;
                pk.x = (__float_as_uint(s0) & ~1u) | ee0;
                pk.y = (__float_as_uint(s1) & ~1u) | ee1;
                pk.z = (__float_as_uint(s2) & ~1u) | ee0;
                pk.w = (__float_as_uint(s3) & ~1u) | ee1;
                char* dst = (char*)hvt + (size_t)((t + 1) & 1) * PARBYTES +
                            (size_t)(r0 + tid) * 4;
                // Store-store fence: prior-step publishes must be at the
                // coherence point before this step's publish issues (~free).
                asm volatile("s_waitcnt vmcnt(0)" ::: "memory");
#pragma unroll
                for (int rep = 0; rep < NREP; ++rep)
                    st16_sc1(dst + (size_t)rep * (2 * PARBYTES), pk);
            }
            // out[] writes AFTER the publish so the fence never waits on them.
            out[(size_t)t * H + r0 + tid] = val;                  // h_t over U
            if (t == S - 1) out[(size_t)S * H + r0 + tid] = val;  // h_T
        }
        // No trailing barrier: next step's partials go to part[(t+1)&1]; reuse
        // of part[t&1] at t+2 is gated by the global dataflow (skew <= 1 step).
    }
}

extern "C" void kernel_launch(void* const* d_in, const int* in_sizes, int n_in,
                              void* d_out, int out_size, void* d_ws, size_t ws_size,
                              hipStream_t stream) {
    const float* X    = (const float*)d_in[0];  // (8192, 2048)
    const float* Wxh  = (const float*)d_in[1];  // (2048, 2048)
    const float* Whh  = (const float*)d_in[2];  // (2048, 2048)
    const float* bias = (const float*)d_in[3];  // (2048,)
    float* out = (float*)d_out;
    unsigned long long* hvt = (unsigned long long*)d_ws;   // 32 KB

    // Phase 0: init replicated packed h buffers.
    init_ws<<<(NREP * 2 * (PARBYTES / 8) + 255) / 256, 256, 0, stream>>>(hvt);

    // Phase 1: U = X @ Wxh^T into out[0 .. S*H)
    dim3 ggrid(S / 64, H / 64);
    gemm_xw<<<ggrid, 256, 0, stream>>>(X, Wxh, out);

    // Phase 2: sequential recurrence (cooperative launch; data-flow sync).
    void* args[] = {(void*)&out, (void*)&Whh, (void*)&bias, (void*)&hvt};
    hipLaunchCooperativeKernel((void*)rnn_recur, dim3(NBLK), dim3(TPB), args, 0, stream);
}

// Round 10
// 19510.718 us; speedup vs baseline: 1.0588x; 1.0588x over previous
//
#include <hip/hip_runtime.h>
#include <math.h>

#define H 2048
#define S 8192
#define RPB 16             // hidden rows per block
#define NBLK (H / RPB)     // 128 blocks
#define PARBYTES (H * 4)   // 8 KB per parity buffer (2048 packed fp32)
#define NREP 2             // hvt replicas
// ws layout (bytes): [rep][parity][PARBYTES] = 2*2*8KB = 32 KB

typedef unsigned int u32x4 __attribute__((ext_vector_type(4)));

// ---------------------------------------------------------------------------
// GEMM: U[t][j] = sum_k X[t][k] * Wxh[j][k]  (unchanged; ~1 ms, not the bottleneck)
// ---------------------------------------------------------------------------
__global__ __launch_bounds__(256) void gemm_xw(const float* __restrict__ X,
                                               const float* __restrict__ W,
                                               float* __restrict__ U) {
    __shared__ float As[16][64];
    __shared__ float Bs[16][64];
    const int tid = threadIdx.x;
    const int t0 = blockIdx.x * 64;
    const int j0 = blockIdx.y * 64;
    const int tx = tid & 15, ty = tid >> 4;

    float acc[4][4] = {};
    const int lr = tid >> 2;
    const int lk = (tid & 3) * 4;

    for (int k0 = 0; k0 < H; k0 += 16) {
        float4 a = *(const float4*)&X[(size_t)(t0 + lr) * H + k0 + lk];
        float4 b = *(const float4*)&W[(size_t)(j0 + lr) * H + k0 + lk];
        As[lk + 0][lr] = a.x; As[lk + 1][lr] = a.y; As[lk + 2][lr] = a.z; As[lk + 3][lr] = a.w;
        Bs[lk + 0][lr] = b.x; Bs[lk + 1][lr] = b.y; Bs[lk + 2][lr] = b.z; Bs[lk + 3][lr] = b.w;
        __syncthreads();
#pragma unroll
        for (int kk = 0; kk < 16; ++kk) {
            float4 av = *(const float4*)&As[kk][ty * 4];
            float4 bv = *(const float4*)&Bs[kk][tx * 4];
            float aa[4] = {av.x, av.y, av.z, av.w};
            float bb[4] = {bv.x, bv.y, bv.z, bv.w};
#pragma unroll
            for (int i = 0; i < 4; ++i)
#pragma unroll
                for (int j = 0; j < 4; ++j)
                    acc[i][j] += aa[i] * bb[j];
        }
        __syncthreads();
    }
#pragma unroll
    for (int i = 0; i < 4; ++i) {
        float4 v = {acc[i][0], acc[i][1], acc[i][2], acc[i][3]};
        *(float4*)&U[(size_t)(t0 + ty * 4 + i) * H + j0 + tx * 4] = v;
    }
}

// ---------------------------------------------------------------------------
// Init. 2-bit epoch e=(t>>1)&3 is spread over a 16B chunk's four LSBs as
// [e&1, e>>1, e&1, e>>1]. Parity-0 init = all-zero (value 0 = h0, pattern
// e=0 -> matches t=0). Parity-1 init = LSB 1 per 4B (pattern e=3, mismatches
// t=1's expected e=0).
// ---------------------------------------------------------------------------
__global__ void init_ws(unsigned long long* __restrict__ w) {
    int i = blockIdx.x * blockDim.x + threadIdx.x;
    if (i < NREP * 2 * (PARBYTES / 8))
        w[i] = ((i >> 10) & 1) ? 0x0000000100000001ull : 0ull;
}

// ---------------------------------------------------------------------------
// sc1 (LLC-coherent) helpers. poll2: thread's two adjacent 16B chunks in one
// vmcnt bundle. Round body minimal: detection quantum ~= 1 LLC RTT.
// ---------------------------------------------------------------------------
__device__ inline void poll2(const void* pc, u32x4& c0, u32x4& c1) {
    asm volatile(
        "global_load_dwordx4 %0, %2, off sc1\n\t"
        "global_load_dwordx4 %1, %2, off offset:16 sc1\n\t"
        "s_waitcnt vmcnt(0)"
        : "=&v"(c0), "=&v"(c1)
        : "v"(pc)
        : "memory");
}
__device__ inline void st16_sc1(void* p, u32x4 v) {
    asm volatile("global_store_dwordx4 %0, %1, off sc1" :: "v"(p), "v"(v) : "memory");
}

// ---------------------------------------------------------------------------
// Persistent recurrence (128 blocks x 16 rows) — the R6-verified kernel,
// restored verbatim after R7/R9 correctness failures (both traced to
// compiler-owned in-flight load registers in fancier poll structures).
//  - publisher store-store fence (s_waitcnt vmcnt(0)) before each publish:
//    orders successive parity-buffer publishes at the coherence point so a
//    consumer can never see tag t-1 while the t-2 slot still holds t-4.
//  - 2-bit epoch spread over chunk LSBs -> 8-step alias distance.
//  - per-4B atomicity + chunk-unit validation (tear-safe); poll/check/FMA
//    all in one blocking round (no in-flight registers cross asm blocks).
//  - skew<=1-step dataflow bound; part[] parity double-buffer.
// ---------------------------------------------------------------------------
__global__ __launch_bounds__(256) void rnn_recur(float* __restrict__ out,
                                                 const float* __restrict__ Whh,
                                                 const float* __restrict__ bias,
                                                 unsigned long long* __restrict__ hvt) {
    __shared__ float part[2][4][RPB];   // [parity][wave][row]
    const int tid  = threadIdx.x;
    const int lane = tid & 63;
    const int wid  = tid >> 6;
    const int r0   = blockIdx.x * RPB;

    // W fragment: wv[j][i] = Whh[r0+j][8*tid + 4*i .. +3]  (128 VGPRs)
    float4 wv[RPB][2];
#pragma unroll
    for (int j = 0; j < RPB; ++j)
#pragma unroll
        for (int i = 0; i < 2; ++i)
            wv[j][i] = *(const float4*)&Whh[(size_t)(r0 + j) * H + 8 * tid + 4 * i];

    const float bb = bias[r0 + (tid & 15)];
    char* const hrep = (char*)hvt + (size_t)(blockIdx.x & 1) * (2 * PARBYTES);

    for (int t = 0; t < S; ++t) {
        // Prefetch this step's U value (rows r0..r0+15; hides under poll).
        float u_val = out[(size_t)t * H + r0 + (tid & 15)];

        const unsigned int e  = ((unsigned int)t >> 1) & 3u;
        const unsigned int e0 = e & 1u, e1 = (e >> 1) & 1u;
        const char* pc = hrep + (size_t)(t & 1) * PARBYTES + tid * 32;

        float acc[RPB] = {};
        unsigned int pend = 3u;
        while (pend) {
            u32x4 c0, c1;
            poll2(pc, c0, c1);
#pragma unroll
            for (int i = 0; i < 2; ++i) {
                if (pend & (1u << i)) {
                    const u32x4 v = i ? c1 : c0;
                    if ((((v.x ^ e0) | (v.z ^ e0) | (v.y ^ e1) | (v.w ^ e1)) & 1u) == 0u) {
                        const float h0 = __uint_as_float(v.x), h1 = __uint_as_float(v.y);
                        const float h2 = __uint_as_float(v.z), h3 = __uint_as_float(v.w);
#pragma unroll
                        for (int j = 0; j < RPB; ++j)
                            acc[j] += wv[j][i].x * h0 + wv[j][i].y * h1 +
                                      wv[j][i].z * h2 + wv[j][i].w * h3;
                        pend &= ~(1u << i);
                    }
                }
            }
        }

        // Folding butterfly: 16 rows x 64 lanes -> 1 row/lane (depth 6).
#pragma unroll
        for (int j = 0; j < 8; ++j) {
            float s = (lane & 1) ? acc[j] : acc[j + 8];
            float r = __shfl_xor(s, 1, 64);
            acc[j] = ((lane & 1) ? acc[j + 8] : acc[j]) + r;
        }
#pragma unroll
        for (int j = 0; j < 4; ++j) {
            float s = (lane & 2) ? acc[j] : acc[j + 4];
            float r = __shfl_xor(s, 2, 64);
            acc[j] = ((lane & 2) ? acc[j + 4] : acc[j]) + r;
        }
#pragma unroll
        for (int j = 0; j < 2; ++j) {
            float s = (lane & 4) ? acc[j] : acc[j + 2];
            float r = __shfl_xor(s, 4, 64);
            acc[j] = ((lane & 4) ? acc[j + 2] : acc[j]) + r;
        }
        {
            float s = (lane & 8) ? acc[0] : acc[1];
            float r = __shfl_xor(s, 8, 64);
            acc[0] = ((lane & 8) ? acc[1] : acc[0]) + r;
        }
        acc[0] += __shfl_xor(acc[0], 16, 64);
        acc[0] += __shfl_xor(acc[0], 32, 64);

        // lane<16 holds row bitrev4(lane&15).
        if (lane < 16) {
            const int row = ((lane & 1) << 3) | ((lane & 2) << 1) |
                            ((lane & 4) >> 1) | ((lane & 8) >> 3);
            part[t & 1][wid][row] = acc[0];
        }
        __syncthreads();

        if (tid < RPB) {
            const float sum = part[t & 1][0][tid] + part[t & 1][1][tid] +
                              part[t & 1][2][tid] + part[t & 1][3][tid];
            const float val = tanhf(sum + u_val + bb);
            // Gather 4 adjacent rows into one 16B word; lanes 0,4,8,12 store.
            const float s0 = __shfl(val, (tid & 12) | 0, 64);
            const float s1 = __shfl(val, (tid & 12) | 1, 64);
            const float s2 = __shfl(val, (tid & 12) | 2, 64);
            const float s3 = __shfl(val, (tid & 12) | 3, 64);
            if ((tid & 3) == 0) {
                const unsigned int ee  = (((unsigned int)(t + 1)) >> 1) & 3u;
                const unsigned int ee0 = ee & 1u, ee1 = (ee >> 1) & 1u;
                u32x4 pk;
                pk.x = (__float_as_uint(s0) & ~1u) | ee0;
                pk.y = (__float_as_uint(s1) & ~1u) | ee1;
                pk.z = (__float_as_uint(s2) & ~1u) | ee0;
                pk.w = (__float_as_uint(s3) & ~1u) | ee1;
                char* dst = (char*)hvt + (size_t)((t + 1) & 1) * PARBYTES +
                            (size_t)(r0 + tid) * 4;
                // Store-store fence: prior-step publishes must be at the
                // coherence point before this step's publish issues (~free).
                asm volatile("s_waitcnt vmcnt(0)" ::: "memory");
#pragma unroll
                for (int rep = 0; rep < NREP; ++rep)
                    st16_sc1(dst + (size_t)rep * (2 * PARBYTES), pk);
            }
            // out[] writes AFTER the publish so the fence never waits on them.
            out[(size_t)t * H + r0 + tid] = val;                  // h_t over U
            if (t == S - 1) out[(size_t)S * H + r0 + tid] = val;  // h_T
        }
        // No trailing barrier: next step's partials go to part[(t+1)&1]; reuse
        // of part[t&1] at t+2 is gated by the global dataflow (skew <= 1 step).
    }
}

extern "C" void kernel_launch(void* const* d_in, const int* in_sizes, int n_in,
                              void* d_out, int out_size, void* d_ws, size_t ws_size,
                              hipStream_t stream) {
    const float* X    = (const float*)d_in[0];  // (8192, 2048)
    const float* Wxh  = (const float*)d_in[1];  // (2048, 2048)
    const float* Whh  = (const float*)d_in[2];  // (2048, 2048)
    const float* bias = (const float*)d_in[3];  // (2048,)
    float* out = (float*)d_out;
    unsigned long long* hvt = (unsigned long long*)d_ws;   // 32 KB

    // Phase 0: init replicated packed h buffers.
    init_ws<<<(NREP * 2 * (PARBYTES / 8) + 255) / 256, 256, 0, stream>>>(hvt);

    // Phase 1: U = X @ Wxh^T into out[0 .. S*H)
    dim3 ggrid(S / 64, H / 64);
    gemm_xw<<<ggrid, 256, 0, stream>>>(X, Wxh, out);

    // Phase 2: sequential recurrence (cooperative launch; data-flow sync).
    void* args[] = {(void*)&out, (void*)&Whh, (void*)&bias, (void*)&hvt};
    hipLaunchCooperativeKernel((void*)rnn_recur, dim3(NBLK), dim3(256), args, 0, stream);
}